// Round 6
// baseline (329.214 us; speedup 1.0000x reference)
//
#include <hip/hip_runtime.h>

// NonlocalWeightedAverage v5: grid 512 = (b, ny, q-half), 512 threads,
// 2 blocks/CU (LDS 81408 B). Per block: convert q rows + stream key rows
// fp32->bf16 through a 3-slot LDS ring; 9-shift MFMA (16x16x32 bf16) with
// dy-reuse; fixed-max softmax via negM. Waves: 2 qg x 4 kq (16q x 16k).

#define NPIX 4096
#define ROWCH 528              // 8 kchunks * 66 xslots (xslot 0,65 zero pad)
#define ROWB  (ROWCH * 16)     // 8448 B
#define SCALE 10.0f

typedef __attribute__((ext_vector_type(8))) short bf16x8;
typedef __attribute__((ext_vector_type(4))) float f32x4;

#define MF(a, b, c) __builtin_amdgcn_mfma_f32_16x16x32_bf16(a, b, c, 0, 0, 0)

__device__ __forceinline__ uint4 pack8(const float* v) {
    unsigned h[8];
#pragma unroll
    for (int j = 0; j < 8; ++j) {
        unsigned u = __float_as_uint(v[j]);
        u = u + 0x7fffu + ((u >> 16) & 1u);   // RNE to bf16
        h[j] = u >> 16;
    }
    return (uint4){h[0] | (h[1] << 16), h[2] | (h[3] << 16),
                   h[4] | (h[5] << 16), h[6] | (h[7] << 16)};
}

__device__ __forceinline__ void load_row(const float* fr, int kc, int x, float* L) {
#pragma unroll
    for (int j = 0; j < 8; ++j) L[j] = fr[(size_t)(kc * 8 + j) * NPIX + x];
}

// 6 MFMAs into target slot T with AF base index DBASE (= q-side dy * 3)
#define MFMA_GRP(T, DBASE) do {                                               \
    _Pragma("unroll")                                                         \
    for (int dx = 0; dx < 3; ++dx)                                            \
        _Pragma("unroll")                                                     \
        for (int ks = 0; ks < 2; ++ks)                                        \
            acc[T] = MF(AF[((DBASE) + dx) * 2 + ks], Bf[ks][dx], acc[T]);     \
} while (0)

#define RETIRE(S, myv) do {                                                   \
    const int kx = kq * 16 + nl;                                              \
    const float xv0 = xls[(myv) * 64 + kx];                                   \
    const float xv1 = xls[NPIX + (myv) * 64 + kx];                            \
    const float xv2 = xls[2 * NPIX + (myv) * 64 + kx];                        \
    _Pragma("unroll")                                                         \
    for (int rg = 0; rg < 4; ++rg) {                                          \
        const float e = __expf(fmaf(acc[S][rg], SCALE, negM[rg]));            \
        l_[rg] += e;                                                          \
        A0[rg] = fmaf(e, xv0, A0[rg]);                                        \
        A1[rg] = fmaf(e, xv1, A1[rg]);                                        \
        A2[rg] = fmaf(e, xv2, A2[rg]);                                        \
    }                                                                         \
    acc[S] = (f32x4){0.f, 0.f, 0.f, 0.f};                                     \
} while (0)

// Ring slots: read RM (= r%3); write row r+2 into SR (=(r+2)%3); SN=(r+1)%3.
#define STEP(RM, SN, SR, rr) do {                                             \
    const int r_ = (rr);                                                      \
    if (r_ <= 61) *(uint4*)(ring + (SR) * ROWB + wu16) = pack8(L);            \
    if (r_ <= 60) load_row(featb + (r_ + 3) * 64, kc, x, L);                  \
    if (r_ < 64) {                                                            \
        const char* base = ring + (RM) * ROWB + bu;                           \
        bf16x8 Bf[2][3];                                                      \
        _Pragma("unroll")                                                     \
        for (int ks = 0; ks < 2; ++ks) {                                      \
            const char* p = base + ks * 4224;                                 \
            Bf[ks][0] = *(const bf16x8*)(p);                                  \
            Bf[ks][1] = *(const bf16x8*)(p + 16);                             \
            Bf[ks][2] = *(const bf16x8*)(p + 32);                             \
        }                                                                     \
        if (r_ >= 1)     MFMA_GRP(SR, 6);   /* my=r-1, dy=2 (final) */        \
        MFMA_GRP(RM, 3);                    /* my=r,   dy=1 */                \
        if (r_ + 1 < 64) MFMA_GRP(SN, 0);   /* my=r+1, dy=0 */                \
    }                                                                         \
    if (r_ >= 1 && r_ <= 64) RETIRE(SR, r_ - 1);                              \
    if (r_ < 64) __syncthreads();                                             \
} while (0)

__global__ __launch_bounds__(512, 4)
void nlwa_fused(const float* __restrict__ x_lab,
                const float* __restrict__ feature,
                float* __restrict__ out)
{
    __shared__ __align__(16) char ring[3 * ROWB];   // 25344 B
    __shared__ float xls[3 * NPIX];                 // 49152 B
    __shared__ __align__(16) char aux[6144];        // part (start) / scrF (end)
    __shared__ float ssq[3][64];                    // 768 B
                                                    // total 81408 B (<= 80 KiB)
    const int tid = threadIdx.x;
    const int bid = blockIdx.x;
    const int b = bid >> 7, ny = (bid >> 1) & 63, qh = bid & 1;
    const int w = tid >> 6, lane = tid & 63;
    const int quad = lane >> 4, nl = lane & 15;
    const int qg = w & 1, kq = w >> 1;              // q group, key quarter
    const int qofs = qh * 32 + qg * 16;
    const int kc = w, x = lane;                     // staging unit (kchunk, col)
    const int wu16 = (kc * 66 + x + 1) * 16;        // this thread's ds_write slot
    const int bu = (quad * 66 + kq * 16 + nl) * 16; // B fragment lane base

    const float* featb = feature + (size_t)b * 64 * NPIX;
    const float* xb = x_lab + (size_t)b * 3 * NPIX;
    float* part = (float*)aux;                      // [3][8][64]

    // ---- stage x_lab[b] (48 KB) into LDS ----
    {
        const float4* s4 = (const float4*)xb;
        float4* d4 = (float4*)xls;
        for (int i = tid; i < 3 * NPIX / 4; i += 512) d4[i] = s4[i];
    }
    // ---- zero the pad units of all 3 ring slots ----
    if (tid < 48) {
        const int sl = tid / 16, pu = tid % 16;
        const int u = (pu >> 1) * 66 + (pu & 1) * 65;
        *(uint4*)(ring + sl * ROWB + u * 16) = (uint4){0u, 0u, 0u, 0u};
    }

    // ---- convert the 3 query rows into ring slots; ssq partials ----
    float L[8];
#pragma unroll
    for (int dyi = 0; dyi < 3; ++dyi) {
        const int qr = ny + dyi - 1;
        float ss = 0.f;
        if (qr >= 0 && qr < 64) {
            load_row(featb + qr * 64, kc, x, L);
#pragma unroll
            for (int j = 0; j < 8; ++j) ss = fmaf(L[j], L[j], ss);
            *(uint4*)(ring + dyi * ROWB + wu16) = pack8(L);
        } else {
            *(uint4*)(ring + dyi * ROWB + wu16) = (uint4){0u, 0u, 0u, 0u};
        }
        part[(dyi * 8 + kc) * 64 + x] = ss;
    }
    __syncthreads();

    if (tid < 192) {
        const int dyi = tid >> 6, xx = tid & 63;
        float s = 0.f;
#pragma unroll
        for (int k = 0; k < 8; ++k) s += part[(dyi * 8 + k) * 64 + xx];
        ssq[dyi][xx] = s;
    }

    // ---- A fragments: 18 = 9 (dy,dx) x 2 ks, for this wave's 16 queries ----
    bf16x8 AF[18];
#pragma unroll
    for (int dyi = 0; dyi < 3; ++dyi)
#pragma unroll
        for (int dx = 0; dx < 3; ++dx)
#pragma unroll
            for (int ks = 0; ks < 2; ++ks)
                AF[(dyi * 3 + dx) * 2 + ks] = *(const bf16x8*)(ring + dyi * ROWB +
                    ((quad + ks * 4) * 66 + qofs + nl + dx) * 16);
    __syncthreads();   // ssq ready; AF reads drained before ring overwrite

    // ---- fixed softmax offsets ----
    float negM[4];
#pragma unroll
    for (int rg = 0; rg < 4; ++rg) {
        const int q = qofs + quad * 4 + rg;
        float a = 0.f;
#pragma unroll
        for (int dyi = 0; dyi < 3; ++dyi)
#pragma unroll
            for (int dx = -1; dx <= 1; ++dx) {
                const int cx = q + dx;
                a += (cx >= 0 && cx < 64) ? ssq[dyi][cx] : 0.f;
            }
        negM[rg] = -SCALE * a;
    }

    // ---- stage key rows 0,1 into slots 0,1; preload row 2 into L ----
#pragma unroll
    for (int rr = 0; rr < 2; ++rr) {
        load_row(featb + rr * 64, kc, x, L);
        *(uint4*)(ring + rr * ROWB + wu16) = pack8(L);
    }
    load_row(featb + 2 * 64, kc, x, L);

    float l_[4], A0[4], A1[4], A2[4];
#pragma unroll
    for (int rg = 0; rg < 4; ++rg) { l_[rg] = 0.f; A0[rg] = 0.f; A1[rg] = 0.f; A2[rg] = 0.f; }
    f32x4 acc[3];
#pragma unroll
    for (int i = 0; i < 3; ++i) acc[i] = (f32x4){0.f, 0.f, 0.f, 0.f};
    __syncthreads();

    for (int rb = 0; rb < 66; rb += 3) {
        STEP(0, 1, 2, rb);
        STEP(1, 2, 0, rb + 1);
        STEP(2, 0, 1, rb + 2);
    }

    // ---- combine: shfl-reduce 16 key cols, LDS-reduce 4 key quarters ----
#pragma unroll
    for (int rg = 0; rg < 4; ++rg) {
#pragma unroll
        for (int off = 8; off >= 1; off >>= 1) {
            l_[rg] += __shfl_down(l_[rg], off, 16);
            A0[rg] += __shfl_down(A0[rg], off, 16);
            A1[rg] += __shfl_down(A1[rg], off, 16);
            A2[rg] += __shfl_down(A2[rg], off, 16);
        }
    }
    __syncthreads();                 // part dead; reuse aux as scrF [32][4]
    float4* scrF = (float4*)aux;
    if (nl == 0) {
#pragma unroll
        for (int rg = 0; rg < 4; ++rg) {
            const int ql = qg * 16 + quad * 4 + rg;   // q local to block
            scrF[ql * 4 + kq] = make_float4(l_[rg], A0[rg], A1[rg], A2[rg]);
        }
    }
    __syncthreads();
    if (tid < 32) {
        const float4 t0 = scrF[tid * 4 + 0], t1 = scrF[tid * 4 + 1];
        const float4 t2 = scrF[tid * 4 + 2], t3 = scrF[tid * 4 + 3];
        const float inv = 1.0f / (t0.x + t1.x + t2.x + t3.x);
        float* o = out + (size_t)b * 3 * NPIX + ny * 64 + qh * 32 + tid;
        o[0]        = (t0.y + t1.y + t2.y + t3.y) * inv;
        o[NPIX]     = (t0.z + t1.z + t2.z + t3.z) * inv;
        o[2 * NPIX] = (t0.w + t1.w + t2.w + t3.w) * inv;
    }
}

extern "C" void kernel_launch(void* const* d_in, const int* in_sizes, int n_in,
                              void* d_out, int out_size, void* d_ws, size_t ws_size,
                              hipStream_t stream) {
    (void)in_sizes; (void)n_in; (void)out_size; (void)d_ws; (void)ws_size;
    const float* x_lab   = (const float*)d_in[0];
    const float* feature = (const float*)d_in[1];
    float* out = (float*)d_out;
    nlwa_fused<<<dim3(512), dim3(512), 0, stream>>>(x_lab, feature, out);
}

// Round 7
// 155.435 us; speedup vs baseline: 2.1180x; 2.1180x over previous
//
#include <hip/hip_runtime.h>

// NonlocalWeightedAverage v6 == v5 with the register-cap fix:
// __launch_bounds__(512, 2) -> 128-VGPR budget (second arg is min BLOCKS/CU
// on this toolchain; 4 forced a 64-reg cap and spilled everything).
// Grid 512 = (b, ny, q-half), 512 threads, LDS 81408 B => 2 blocks/CU.

#define NPIX 4096
#define ROWCH 528              // 8 kchunks * 66 xslots (xslot 0,65 zero pad)
#define ROWB  (ROWCH * 16)     // 8448 B
#define SCALE 10.0f

typedef __attribute__((ext_vector_type(8))) short bf16x8;
typedef __attribute__((ext_vector_type(4))) float f32x4;

#define MF(a, b, c) __builtin_amdgcn_mfma_f32_16x16x32_bf16(a, b, c, 0, 0, 0)

__device__ __forceinline__ uint4 pack8(const float* v) {
    unsigned h[8];
#pragma unroll
    for (int j = 0; j < 8; ++j) {
        unsigned u = __float_as_uint(v[j]);
        u = u + 0x7fffu + ((u >> 16) & 1u);   // RNE to bf16
        h[j] = u >> 16;
    }
    return (uint4){h[0] | (h[1] << 16), h[2] | (h[3] << 16),
                   h[4] | (h[5] << 16), h[6] | (h[7] << 16)};
}

__device__ __forceinline__ void load_row(const float* fr, int kc, int x, float* L) {
#pragma unroll
    for (int j = 0; j < 8; ++j) L[j] = fr[(size_t)(kc * 8 + j) * NPIX + x];
}

// 6 MFMAs into target slot T with AF base index DBASE (= q-side dy * 3)
#define MFMA_GRP(T, DBASE) do {                                               \
    _Pragma("unroll")                                                         \
    for (int dx = 0; dx < 3; ++dx)                                            \
        _Pragma("unroll")                                                     \
        for (int ks = 0; ks < 2; ++ks)                                        \
            acc[T] = MF(AF[((DBASE) + dx) * 2 + ks], Bf[ks][dx], acc[T]);     \
} while (0)

#define RETIRE(S, myv) do {                                                   \
    const int kx = kq * 16 + nl;                                              \
    const float xv0 = xls[(myv) * 64 + kx];                                   \
    const float xv1 = xls[NPIX + (myv) * 64 + kx];                            \
    const float xv2 = xls[2 * NPIX + (myv) * 64 + kx];                        \
    _Pragma("unroll")                                                         \
    for (int rg = 0; rg < 4; ++rg) {                                          \
        const float e = __expf(fmaf(acc[S][rg], SCALE, negM[rg]));            \
        l_[rg] += e;                                                          \
        A0[rg] = fmaf(e, xv0, A0[rg]);                                        \
        A1[rg] = fmaf(e, xv1, A1[rg]);                                        \
        A2[rg] = fmaf(e, xv2, A2[rg]);                                        \
    }                                                                         \
    acc[S] = (f32x4){0.f, 0.f, 0.f, 0.f};                                     \
} while (0)

// Ring slots: read RM (= r%3); write row r+2 into SR (=(r+2)%3); SN=(r+1)%3.
#define STEP(RM, SN, SR, rr) do {                                             \
    const int r_ = (rr);                                                      \
    if (r_ <= 61) *(uint4*)(ring + (SR) * ROWB + wu16) = pack8(L);            \
    if (r_ <= 60) load_row(featb + (r_ + 3) * 64, kc, x, L);                  \
    if (r_ < 64) {                                                            \
        const char* base = ring + (RM) * ROWB + bu;                           \
        bf16x8 Bf[2][3];                                                      \
        _Pragma("unroll")                                                     \
        for (int ks = 0; ks < 2; ++ks) {                                      \
            const char* p = base + ks * 4224;                                 \
            Bf[ks][0] = *(const bf16x8*)(p);                                  \
            Bf[ks][1] = *(const bf16x8*)(p + 16);                             \
            Bf[ks][2] = *(const bf16x8*)(p + 32);                             \
        }                                                                     \
        if (r_ >= 1)     MFMA_GRP(SR, 6);   /* my=r-1, dy=2 (final) */        \
        MFMA_GRP(RM, 3);                    /* my=r,   dy=1 */                \
        if (r_ + 1 < 64) MFMA_GRP(SN, 0);   /* my=r+1, dy=0 */                \
    }                                                                         \
    if (r_ >= 1 && r_ <= 64) RETIRE(SR, r_ - 1);                              \
    if (r_ < 64) __syncthreads();                                             \
} while (0)

__global__ __launch_bounds__(512, 2)
void nlwa_fused(const float* __restrict__ x_lab,
                const float* __restrict__ feature,
                float* __restrict__ out)
{
    __shared__ __align__(16) char ring[3 * ROWB];   // 25344 B
    __shared__ float xls[3 * NPIX];                 // 49152 B
    __shared__ __align__(16) char aux[6144];        // part (start) / scrF (end)
    __shared__ float ssq[3][64];                    // 768 B
                                                    // total 81408 B (<= 80 KiB)
    const int tid = threadIdx.x;
    const int bid = blockIdx.x;
    const int b = bid >> 7, ny = (bid >> 1) & 63, qh = bid & 1;
    const int w = tid >> 6, lane = tid & 63;
    const int quad = lane >> 4, nl = lane & 15;
    const int qg = w & 1, kq = w >> 1;              // q group, key quarter
    const int qofs = qh * 32 + qg * 16;
    const int kc = w, x = lane;                     // staging unit (kchunk, col)
    const int wu16 = (kc * 66 + x + 1) * 16;        // this thread's ds_write slot
    const int bu = (quad * 66 + kq * 16 + nl) * 16; // B fragment lane base

    const float* featb = feature + (size_t)b * 64 * NPIX;
    const float* xb = x_lab + (size_t)b * 3 * NPIX;
    float* part = (float*)aux;                      // [3][8][64]

    // ---- stage x_lab[b] (48 KB) into LDS ----
    {
        const float4* s4 = (const float4*)xb;
        float4* d4 = (float4*)xls;
        for (int i = tid; i < 3 * NPIX / 4; i += 512) d4[i] = s4[i];
    }
    // ---- zero the pad units of all 3 ring slots ----
    if (tid < 48) {
        const int sl = tid / 16, pu = tid % 16;
        const int u = (pu >> 1) * 66 + (pu & 1) * 65;
        *(uint4*)(ring + sl * ROWB + u * 16) = (uint4){0u, 0u, 0u, 0u};
    }

    // ---- convert the 3 query rows into ring slots; ssq partials ----
    float L[8];
#pragma unroll
    for (int dyi = 0; dyi < 3; ++dyi) {
        const int qr = ny + dyi - 1;
        float ss = 0.f;
        if (qr >= 0 && qr < 64) {
            load_row(featb + qr * 64, kc, x, L);
#pragma unroll
            for (int j = 0; j < 8; ++j) ss = fmaf(L[j], L[j], ss);
            *(uint4*)(ring + dyi * ROWB + wu16) = pack8(L);
        } else {
            *(uint4*)(ring + dyi * ROWB + wu16) = (uint4){0u, 0u, 0u, 0u};
        }
        part[(dyi * 8 + kc) * 64 + x] = ss;
    }
    __syncthreads();

    if (tid < 192) {
        const int dyi = tid >> 6, xx = tid & 63;
        float s = 0.f;
#pragma unroll
        for (int k = 0; k < 8; ++k) s += part[(dyi * 8 + k) * 64 + xx];
        ssq[dyi][xx] = s;
    }

    // ---- A fragments: 18 = 9 (dy,dx) x 2 ks, for this wave's 16 queries ----
    bf16x8 AF[18];
#pragma unroll
    for (int dyi = 0; dyi < 3; ++dyi)
#pragma unroll
        for (int dx = 0; dx < 3; ++dx)
#pragma unroll
            for (int ks = 0; ks < 2; ++ks)
                AF[(dyi * 3 + dx) * 2 + ks] = *(const bf16x8*)(ring + dyi * ROWB +
                    ((quad + ks * 4) * 66 + qofs + nl + dx) * 16);
    __syncthreads();   // ssq ready; AF reads drained before ring overwrite

    // ---- fixed softmax offsets ----
    float negM[4];
#pragma unroll
    for (int rg = 0; rg < 4; ++rg) {
        const int q = qofs + quad * 4 + rg;
        float a = 0.f;
#pragma unroll
        for (int dyi = 0; dyi < 3; ++dyi)
#pragma unroll
            for (int dx = -1; dx <= 1; ++dx) {
                const int cx = q + dx;
                a += (cx >= 0 && cx < 64) ? ssq[dyi][cx] : 0.f;
            }
        negM[rg] = -SCALE * a;
    }

    // ---- stage key rows 0,1 into slots 0,1; preload row 2 into L ----
#pragma unroll
    for (int rr = 0; rr < 2; ++rr) {
        load_row(featb + rr * 64, kc, x, L);
        *(uint4*)(ring + rr * ROWB + wu16) = pack8(L);
    }
    load_row(featb + 2 * 64, kc, x, L);

    float l_[4], A0[4], A1[4], A2[4];
#pragma unroll
    for (int rg = 0; rg < 4; ++rg) { l_[rg] = 0.f; A0[rg] = 0.f; A1[rg] = 0.f; A2[rg] = 0.f; }
    f32x4 acc[3];
#pragma unroll
    for (int i = 0; i < 3; ++i) acc[i] = (f32x4){0.f, 0.f, 0.f, 0.f};
    __syncthreads();

    for (int rb = 0; rb < 66; rb += 3) {
        STEP(0, 1, 2, rb);
        STEP(1, 2, 0, rb + 1);
        STEP(2, 0, 1, rb + 2);
    }

    // ---- combine: shfl-reduce 16 key cols, LDS-reduce 4 key quarters ----
#pragma unroll
    for (int rg = 0; rg < 4; ++rg) {
#pragma unroll
        for (int off = 8; off >= 1; off >>= 1) {
            l_[rg] += __shfl_down(l_[rg], off, 16);
            A0[rg] += __shfl_down(A0[rg], off, 16);
            A1[rg] += __shfl_down(A1[rg], off, 16);
            A2[rg] += __shfl_down(A2[rg], off, 16);
        }
    }
    __syncthreads();                 // part dead; reuse aux as scrF [32][4]
    float4* scrF = (float4*)aux;
    if (nl == 0) {
#pragma unroll
        for (int rg = 0; rg < 4; ++rg) {
            const int ql = qg * 16 + quad * 4 + rg;   // q local to block
            scrF[ql * 4 + kq] = make_float4(l_[rg], A0[rg], A1[rg], A2[rg]);
        }
    }
    __syncthreads();
    if (tid < 32) {
        const float4 t0 = scrF[tid * 4 + 0], t1 = scrF[tid * 4 + 1];
        const float4 t2 = scrF[tid * 4 + 2], t3 = scrF[tid * 4 + 3];
        const float inv = 1.0f / (t0.x + t1.x + t2.x + t3.x);
        float* o = out + (size_t)b * 3 * NPIX + ny * 64 + qh * 32 + tid;
        o[0]        = (t0.y + t1.y + t2.y + t3.y) * inv;
        o[NPIX]     = (t0.z + t1.z + t2.z + t3.z) * inv;
        o[2 * NPIX] = (t0.w + t1.w + t2.w + t3.w) * inv;
    }
}

extern "C" void kernel_launch(void* const* d_in, const int* in_sizes, int n_in,
                              void* d_out, int out_size, void* d_ws, size_t ws_size,
                              hipStream_t stream) {
    (void)in_sizes; (void)n_in; (void)out_size; (void)d_ws; (void)ws_size;
    const float* x_lab   = (const float*)d_in[0];
    const float* feature = (const float*)d_in[1];
    float* out = (float*)d_out;
    nlwa_fused<<<dim3(512), dim3(512), 0, stream>>>(x_lab, feature, out);
}